// Round 2
// baseline (383.520 us; speedup 1.0000x reference)
//
#include <hip/hip_runtime.h>

// DIN attention layer: B=2048, L=200, E=128, H=64.  R4: zero-workspace fold.
// R3 post-mortem: async staging was perfectly neutral -> din_attn is already
// BW-saturated on the keys stream (~35 us). The timed total is dominated by
// 800 MiB workspace re-poison fills (~123 us each) + launch overhead. This
// round: fold k0_prep's b-independent weight algebra into each WG's prologue
// (reads W1/W2 directly; they are L2/L3-resident so the extra ~60 KB/WG of
// gathers never touch HBM) and use NO workspace at all. Tests whether the ws
// poison fill is conditional on ws usage (big win) or fixed (small win: one
// fewer launch + no k0).

#define NB 2048
#define LE 128   // E
#define LH 64    // H
#define LL 200   // L

typedef short bf16x8 __attribute__((ext_vector_type(8)));
typedef float f32x4 __attribute__((ext_vector_type(4)));

__device__ __forceinline__ short f2bf(float f) {  // RNE float->bf16
  unsigned u = __float_as_uint(f);
  u += 0x7fffu + ((u >> 16) & 1u);
  return (short)(u >> 16);
}

__device__ __forceinline__ void gll16(const void* g, void* l) {
  __builtin_amdgcn_global_load_lds(
      (const __attribute__((address_space(1))) void*)g,
      (__attribute__((address_space(3))) void*)l, 16, 0, 0);
}

struct __align__(16) SM {
  union {
    float stag[4][2][16 * 128];  // 65536 B: per-wave dbuf f32 key tiles
    short scratch[64 * 136];     // prologue Wk overlay (dead before staging)
  } u;
  short h1[4][16 * 72];  // 9216 B; overlays: bias partials (prologue), redf (wsum)
  float scores[208];
  float q[128];
  float bias1[64];
  float b2s[64];
  float w3s[64];
  float red[16];
};  // total 76928 B -> 2 WG/CU

__global__ void __launch_bounds__(256, 2)
din_attn(const float* __restrict__ query, const float* __restrict__ keysg,
         const int* __restrict__ mask, const float* __restrict__ W1,
         const float* __restrict__ b1, const float* __restrict__ W2,
         const float* __restrict__ b2, const float* __restrict__ W3,
         const float* __restrict__ no_hist, float* __restrict__ out)
{
  __shared__ SM sm;
  const int b    = blockIdx.x;
  const int t    = threadIdx.x;
  const int lane = t & 63;
  const int wv   = t >> 6;
  const int col  = lane & 15;   // MFMA m/n index
  const int quad = lane >> 4;   // MFMA k-group
  const int l31  = lane & 31;
  const int lh   = lane >> 5;

  // ---- prologue: tiny loads
  int my_mask = 0;
  if (t < LL) my_mask = mask[b * LL + t];
  if (t < LE) sm.q[t] = query[b * LE + t];
  if (t < LH) { sm.b2s[t] = b2[t]; sm.w3s[t] = W3[t]; }
  __syncthreads();  // q visible

  // layer-2 B-frags directly from W2 (L2-cached gathers): frag elem j is
  // bf16(W2[k][c]) with c = n*16+col, k = k2*32+quad*8+j.
  bf16x8 fB2[4][2];
  #pragma unroll
  for (int n = 0; n < 4; ++n) {
    const int c = n * 16 + col;
    #pragma unroll
    for (int k2 = 0; k2 < 2; ++k2) {
      const int k0 = k2 * 32 + quad * 8;
      bf16x8 v;
      #pragma unroll
      for (int j = 0; j < 8; ++j) v[j] = f2bf(W2[(k0 + j) * LH + c]);
      fB2[n][k2] = v;
    }
  }

  // Wk[h][e] = (W1b - W1d) + q_e * W1c -> bf16 scratch (overlaid on staging)
  short* scratch = &sm.u.scratch[0];  // 64 rows x 136 shorts
  #pragma unroll
  for (int i = 0; i < 4; ++i) {
    int idx = (t + 256 * i) * 8;
    int h = idx >> 7, e0 = idx & 127;
    bf16x8 w;
    #pragma unroll
    for (int j = 0; j < 8; ++j) {
      int e = e0 + j;
      float bd = W1[(128 + e) * LH + h] - W1[(384 + e) * LH + h];
      float cq = W1[(256 + e) * LH + h];
      w[j] = f2bf(bd + sm.q[e] * cq);
    }
    *(bf16x8*)&scratch[h * 136 + e0] = w;
  }
  // bias1 partials: wave wv sums e-quarter wv of q_e*(W1a+W1d)[e][h]
  {
    int h = lane;
    float acc = 0.f;
    #pragma unroll 8
    for (int e = wv * 32; e < wv * 32 + 32; ++e)
      acc = fmaf(sm.q[e], W1[e * LH + h] + W1[(384 + e) * LH + h], acc);
    float* biasp = (float*)&sm.h1[0][0];  // 4 x 64 floats
    biasp[wv * 64 + h] = acc;
  }
  __syncthreads();  // barrier A: scratch + partials visible

  bf16x8 fB1[4][4];
  #pragma unroll
  for (int n = 0; n < 4; ++n)
    #pragma unroll
    for (int kt = 0; kt < 4; ++kt)
      fB1[n][kt] = *(const bf16x8*)&scratch[(n * 16 + col) * 136 + kt * 32 + quad * 8];

  if (t < LH) {
    const float* biasp = (const float*)&sm.h1[0][0];
    sm.bias1[t] = b1[t] + biasp[t] + biasp[64 + t] + biasp[128 + t] + biasp[192 + t];
  }
  __syncthreads();  // barrier B: frags read (scratch dead -> staging may begin)

  // ---- barrier-free async main loop: wave wv owns tiles {wv, wv+4, wv+8} (+12 for wv==0)
  const float* kb = keysg + (size_t)b * LL * LE;
  short* h1w = &sm.h1[wv][0];
  const int mts[4] = {wv, wv + 4, wv + 8, 12};
  const int nt = (wv == 0) ? 4 : 3;
  float* stg0 = &sm.u.stag[wv][0][0];
  float* stg1 = &sm.u.stag[wv][1][0];

  // 8 x global_load_lds dwordx4 per 16x128 f32 tile. Instruction i covers
  // staging rows 2i,2i+1 (one aligned 1 KiB global span). 16B blocks are
  // XOR-swizzled by (row&7) via the per-lane GLOBAL address (dest linear).
  auto issue_tile = [&](float* dst, int mt) {
    #pragma unroll
    for (int i = 0; i < 8; ++i) {
      int rl  = 2 * i + lh;              // staging-local row 0..15
      int row = mt * 16 + rl;
      row = row < LL ? row : LL - 1;     // clamp only matters for mt==12
      const float* src = kb + row * LE + ((l31 ^ (rl & 7)) << 2);
      gll16(src, dst + i * 256);
    }
  };

  // staging -> bf16 A-frags; reads are 2-way (free) thanks to the swizzle
  auto load_frags = [&](const float* sb, bf16x8 (&a)[4]) {
    #pragma unroll
    for (int kt = 0; kt < 4; ++kt) {
      const int b0 = kt * 8 + quad * 2;  // 16B block index 0..31
      float4 v0 = *(const float4*)&sb[col * 128 + ((b0 ^ (col & 7)) << 2)];
      float4 v1 = *(const float4*)&sb[col * 128 + (((b0 + 1) ^ (col & 7)) << 2)];
      bf16x8 av;
      av[0] = f2bf(v0.x); av[1] = f2bf(v0.y); av[2] = f2bf(v0.z); av[3] = f2bf(v0.w);
      av[4] = f2bf(v1.x); av[5] = f2bf(v1.y); av[6] = f2bf(v1.z); av[7] = f2bf(v1.w);
      a[kt] = av;
    }
  };

  auto compute_tile = [&](const bf16x8 (&a)[4], int mt) {
    #pragma unroll
    for (int n = 0; n < 4; ++n) {
      f32x4 acc = {0.f, 0.f, 0.f, 0.f};
      #pragma unroll
      for (int kt = 0; kt < 4; ++kt)
        acc = __builtin_amdgcn_mfma_f32_16x16x32_bf16(a[kt], fB1[n][kt], acc, 0, 0, 0);
      float bias = sm.bias1[n * 16 + col];
      #pragma unroll
      for (int j = 0; j < 4; ++j)  // C layout: row=quad*4+j, col
        h1w[(quad * 4 + j) * 72 + n * 16 + col] = f2bf(fmaxf(acc[j] + bias, 0.f));
    }
    bf16x8 a2[2];  // wave-local LDS round-trip (no __syncthreads needed)
    #pragma unroll
    for (int k2 = 0; k2 < 2; ++k2)
      a2[k2] = *(const bf16x8*)&h1w[col * 72 + k2 * 32 + quad * 8];
    float p[4] = {0.f, 0.f, 0.f, 0.f};
    #pragma unroll
    for (int n = 0; n < 4; ++n) {
      f32x4 c2 = {0.f, 0.f, 0.f, 0.f};
      c2 = __builtin_amdgcn_mfma_f32_16x16x32_bf16(a2[0], fB2[n][0], c2, 0, 0, 0);
      c2 = __builtin_amdgcn_mfma_f32_16x16x32_bf16(a2[1], fB2[n][1], c2, 0, 0, 0);
      float bb = sm.b2s[n * 16 + col];
      float w3 = sm.w3s[n * 16 + col];
      #pragma unroll
      for (int j = 0; j < 4; ++j)
        p[j] = fmaf(fmaxf(c2[j] + bb, 0.f), w3, p[j]);  // layer 3 fused; b3 dropped
    }
    #pragma unroll
    for (int j = 0; j < 4; ++j) {
      #pragma unroll
      for (int off = 1; off < 16; off <<= 1)
        p[j] += __shfl_xor(p[j], off);  // reduce over 16 cols
      if (col == 0) sm.scores[mt * 16 + quad * 4 + j] = p[j];
    }
  };

  issue_tile(stg0, mts[0]);   // 8 outstanding
  issue_tile(stg1, mts[1]);   // 16 outstanding

  bf16x8 ka[4][4];  // keys stay resident for the weighted sum (static idx only)
  #pragma unroll
  for (int i = 0; i < 4; ++i) {
    if (i < nt) {
      // counted wait: tile i complete, next tile's 8 loads stay in flight
      if (i < nt - 1) asm volatile("s_waitcnt vmcnt(8)" ::: "memory");
      else            asm volatile("s_waitcnt vmcnt(0)" ::: "memory");
      __builtin_amdgcn_sched_barrier(0);
      load_frags((i & 1) ? stg1 : stg0, ka[i]);
      asm volatile("s_waitcnt lgkmcnt(0)" ::: "memory");  // staging reads done
      __builtin_amdgcn_sched_barrier(0);
      if (i + 2 < nt) issue_tile((i & 1) ? stg1 : stg0, mts[i + 2]);
      __builtin_amdgcn_sched_barrier(0);  // pin prefetch issue before MFMAs
      compute_tile(ka[i], mts[i]);
    }
  }
  __syncthreads();  // scores complete

  // ---- masked softmax over L (fp32; matches ref incl. all-pad handling)
  float sc = (t < LL) ? sm.scores[t] : -3.0e38f;
  float vmax = (my_mask != 0) ? sc : -3.0e38f;
  #pragma unroll
  for (int off = 1; off < 64; off <<= 1) vmax = fmaxf(vmax, __shfl_xor(vmax, off));
  if (lane == 0) sm.red[wv] = vmax;
  __syncthreads();
  float M = fmaxf(fmaxf(sm.red[0], sm.red[1]), fmaxf(sm.red[2], sm.red[3]));
  float ex = (t < LL && my_mask != 0) ? __expf(sc - M) : 0.f;
  float vsum = ex;
  #pragma unroll
  for (int off = 1; off < 64; off <<= 1) vsum += __shfl_xor(vsum, off);
  if (lane == 0) sm.red[4 + wv] = vsum;
  __syncthreads();
  float Z = sm.red[4] + sm.red[5] + sm.red[6] + sm.red[7];
  bool allpad = !(Z > 0.f);
  float rz = allpad ? 0.f : (1.f / Z);
  if (t < 208) sm.scores[t] = (t < LL) ? ex * rz : 0.f;
  __syncthreads();

  // ---- weighted sum from register-resident keys:
  // lane holds keys[mts[i]*16+col][kt*32+quad*8 .. +7]; reduce over col.
  {
    float aw[4] = {0.f, 0.f, 0.f, 0.f};
    #pragma unroll
    for (int i = 0; i < 4; ++i)
      if (i < nt) aw[i] = sm.scores[mts[i] * 16 + col];  // rows>=200 -> 0

    float* redf = (float*)&sm.h1[0][0];  // 4 x 128 floats (h1 dead)
    #pragma unroll
    for (int kt = 0; kt < 4; ++kt) {
      float s[8] = {0.f, 0.f, 0.f, 0.f, 0.f, 0.f, 0.f, 0.f};
      #pragma unroll
      for (int i = 0; i < 4; ++i) {
        if (i < nt) {
          const int* kv = (const int*)&ka[i][kt];
          #pragma unroll
          for (int w = 0; w < 4; ++w) {
            unsigned u = (unsigned)kv[w];
            s[2 * w]     = fmaf(aw[i], __uint_as_float(u << 16), s[2 * w]);
            s[2 * w + 1] = fmaf(aw[i], __uint_as_float(u & 0xffff0000u), s[2 * w + 1]);
          }
        }
      }
      #pragma unroll
      for (int j = 0; j < 8; ++j) {
        #pragma unroll
        for (int off = 1; off < 16; off <<= 1)
          s[j] += __shfl_xor(s[j], off);  // reduce over the 16 cols (rows)
      }
      if (col == 0) {
        #pragma unroll
        for (int j = 0; j < 8; ++j)
          redf[wv * 128 + kt * 32 + quad * 8 + j] = s[j];
      }
    }
    __syncthreads();
    if (t < LE) {
      float s = redf[t] + redf[128 + t] + redf[256 + t] + redf[384 + t];
      if (allpad) s = no_hist[t];
      out[b * LE + t] = s;
    }
  }
}

extern "C" void kernel_launch(void* const* d_in, const int* in_sizes, int n_in,
                              void* d_out, int out_size, void* d_ws, size_t ws_size,
                              hipStream_t stream) {
  (void)in_sizes; (void)n_in; (void)ws_size; (void)out_size; (void)d_ws;
  const float* query   = (const float*)d_in[0];
  const float* keysg   = (const float*)d_in[1];
  const int*   mask    = (const int*)d_in[2];
  const float* W1      = (const float*)d_in[3];
  const float* b1      = (const float*)d_in[4];
  const float* W2      = (const float*)d_in[5];
  const float* b2      = (const float*)d_in[6];
  const float* W3      = (const float*)d_in[7];
  // d_in[8] = b3: unused (softmax shift-invariant)
  const float* no_hist = (const float*)d_in[9];

  // Single launch; no workspace usage at all (tests ws re-poison semantics).
  din_attn<<<NB, 256, 0, stream>>>(query, keysg, mask, W1, b1, W2, b2, W3,
                                   no_hist, (float*)d_out);
}

// Round 3
// 319.612 us; speedup vs baseline: 1.2000x; 1.2000x over previous
//
#include <hip/hip_runtime.h>

// DIN attention layer: B=2048, L=200, E=128, H=64.  R5: occupancy + no-spill.
// R4 post-mortem: per-WG transposed W1 gathers cost +90us; VGPR_Count=108 vs
// live-set >=160 proves the compiler was spilling ka/fB1/fB2 to scratch; only
// 2 WG/CU. This round: (1) weight MFMA fragments live in LDS frag-major
// (per-lane-contiguous 16B -> conflict-free ds_read_b128), freeing 96 VGPRs;
// (2) drop the 64KB async staging (R3 proved neutral) -> direct register
// float4 key loads (R0-validated), keys stay resident in ka for the wsum;
// (3) LDS 77->36KB + __launch_bounds__(256,4) -> 4 WG/CU, 16 waves;
// (4) cheap coalesced prologue restored via __device__ globals written by
// k0_prep each launch (d_ws completely unused -> clean fill-semantics read).

#define NB 2048
#define LE 128   // E
#define LH 64    // H
#define LL 200   // L

typedef short bf16x8 __attribute__((ext_vector_type(8)));
typedef float f32x4 __attribute__((ext_vector_type(4)));

__device__ float g_BD[8192];   // BD[h][e] = W1b - W1d
__device__ float g_Cq[8192];   // Cq[h][e] = W1c
__device__ float g_AD[8192];   // AD[e][h] = W1a + W1d
__device__ short g_W2T[4096];  // W2T[n][k] bf16 (frag-contiguous)

__device__ __forceinline__ short f2bf(float f) {  // RNE float->bf16
  unsigned u = __float_as_uint(f);
  u += 0x7fffu + ((u >> 16) & 1u);
  return (short)(u >> 16);
}

// ---- K0: b-independent weight prep into device globals (no d_ws) ----------
__global__ void k0_prep(const float* __restrict__ W1, const float* __restrict__ W2) {
  int idx = blockIdx.x * 256 + threadIdx.x;  // 32 blocks * 256 = 8192
  if (idx < 8192) {
    int h = idx >> 7, e = idx & 127;
    g_BD[idx] = W1[(128 + e) * LH + h] - W1[(384 + e) * LH + h];
    g_Cq[idx] = W1[(256 + e) * LH + h];
    int e2 = idx >> 6, h2 = idx & 63;
    g_AD[idx] = W1[e2 * LH + h2] + W1[(384 + e2) * LH + h2];
    if (idx < 4096) {
      int c = idx >> 6, k = idx & 63;
      g_W2T[idx] = f2bf(W2[k * LH + c]);
    }
  }
}

struct __align__(16) SM {
  short flds1[16 * 64 * 8];  // 16384 B: W1 frags, frag-major [(n*4+kt)*64+lane]
  short flds2[8 * 64 * 8];   //  8192 B: W2 frags, frag-major [(n*2+k2)*64+lane]
  short h1[4][16 * 72];      //  9216 B; overlays: bias partials, redf (wsum)
  float scores[208];
  float q[128];
  float bias1[64];
  float b2s[64];
  float w3s[64];
  float red[16];
};  // ~35.9 KB -> 4 WG/CU (143.6 KB of 160)

__global__ void __launch_bounds__(256, 4)
din_attn(const float* __restrict__ query, const float* __restrict__ keysg,
         const int* __restrict__ mask, const float* __restrict__ b1,
         const float* __restrict__ b2, const float* __restrict__ W3,
         const float* __restrict__ no_hist, float* __restrict__ out)
{
  __shared__ SM sm;
  const int b    = blockIdx.x;
  const int t    = threadIdx.x;
  const int lane = t & 63;
  const int wv   = t >> 6;
  const int col  = lane & 15;   // MFMA m/n index
  const int quad = lane >> 4;   // MFMA k-group

  // ---- prologue: tiny loads
  int my_mask = 0;
  if (t < LL) my_mask = mask[b * LL + t];
  if (t < LE) sm.q[t] = query[b * LE + t];
  if (t < LH) { sm.b2s[t] = b2[t]; sm.w3s[t] = W3[t]; }
  __syncthreads();  // q visible

  // Wk[h][e] = BD + q_e*Cq -> bf16, written FRAG-MAJOR into flds1.
  // Thread's (h, e0..e0+7) is exactly one frag word: frag (n*4+kt), lane (qd,cc).
  #pragma unroll
  for (int i = 0; i < 4; ++i) {
    int idx = (t + 256 * i) * 8;
    int h = idx >> 7, e0 = idx & 127;
    float4 bd0 = *(const float4*)&g_BD[idx];
    float4 bd1 = *(const float4*)&g_BD[idx + 4];
    float4 c0  = *(const float4*)&g_Cq[idx];
    float4 c1  = *(const float4*)&g_Cq[idx + 4];
    bf16x8 w;
    w[0] = f2bf(bd0.x + sm.q[e0 + 0] * c0.x);
    w[1] = f2bf(bd0.y + sm.q[e0 + 1] * c0.y);
    w[2] = f2bf(bd0.z + sm.q[e0 + 2] * c0.z);
    w[3] = f2bf(bd0.w + sm.q[e0 + 3] * c0.w);
    w[4] = f2bf(bd1.x + sm.q[e0 + 4] * c1.x);
    w[5] = f2bf(bd1.y + sm.q[e0 + 5] * c1.y);
    w[6] = f2bf(bd1.z + sm.q[e0 + 6] * c1.z);
    w[7] = f2bf(bd1.w + sm.q[e0 + 7] * c1.w);
    int n = h >> 4, cc = h & 15, kt = e0 >> 5, qd = (e0 >> 3) & 3;
    *(bf16x8*)&sm.flds1[(((n * 4 + kt) * 64) + qd * 16 + cc) * 8] = w;
  }
  // W2 frags -> flds2 (g_W2T is already frag-contiguous per lane)
  {
    int l = t & 63, f0 = t >> 6;
    #pragma unroll
    for (int ii = 0; ii < 2; ++ii) {
      int f = f0 + ii * 4;  // 0..7
      int n = f >> 1, k2 = f & 1;
      int cc = l & 15, qd = l >> 4;
      *(bf16x8*)&sm.flds2[(f * 64 + l) * 8] =
          *(const bf16x8*)&g_W2T[(n * 16 + cc) * 64 + k2 * 32 + qd * 8];
    }
  }
  // bias1 partials: wave wv sums e-quarter wv (coalesced over h=lane)
  {
    int h = lane;
    float acc = 0.f;
    #pragma unroll 8
    for (int e = wv * 32; e < wv * 32 + 32; ++e)
      acc = fmaf(sm.q[e], g_AD[e * LH + h], acc);
    float* biasp = (float*)&sm.h1[0][0];  // 4 x 64 floats
    biasp[wv * 64 + h] = acc;
  }
  __syncthreads();  // barrier A: flds1/flds2 + partials visible

  if (t < LH) {
    const float* biasp = (const float*)&sm.h1[0][0];
    sm.bias1[t] = b1[t] + biasp[t] + biasp[64 + t] + biasp[128 + t] + biasp[192 + t];
  }
  __syncthreads();  // barrier B: bias1 visible; h1 free for main loop

  // ---- barrier-free main loop: wave wv owns tiles {wv, wv+4, wv+8} (+12 for wv==0)
  const float* kb = keysg + (size_t)b * LL * LE;
  short* h1w = &sm.h1[wv][0];
  const int mts[4] = {wv, wv + 4, wv + 8, 12};
  bf16x8 ka[4][4];  // keys stay resident for the weighted sum

  auto load_tile = [&](bf16x8 (&a)[4], int mt) {
    int row = mt * 16 + col;
    row = row < LL ? row : LL - 1;       // clamp only matters for mt==12
    const float* rp = kb + row * LE;
    #pragma unroll
    for (int kt = 0; kt < 4; ++kt) {
      float4 v0 = *(const float4*)&rp[kt * 32 + quad * 8];
      float4 v1 = *(const float4*)&rp[kt * 32 + quad * 8 + 4];
      bf16x8 av;
      av[0] = f2bf(v0.x); av[1] = f2bf(v0.y); av[2] = f2bf(v0.z); av[3] = f2bf(v0.w);
      av[4] = f2bf(v1.x); av[5] = f2bf(v1.y); av[6] = f2bf(v1.z); av[7] = f2bf(v1.w);
      a[kt] = av;
    }
  };

  auto compute_tile = [&](const bf16x8 (&a)[4], int mt) {
    #pragma unroll
    for (int n = 0; n < 4; ++n) {
      f32x4 acc = {0.f, 0.f, 0.f, 0.f};
      #pragma unroll
      for (int kt = 0; kt < 4; ++kt) {
        bf16x8 wf = *(const bf16x8*)&sm.flds1[((n * 4 + kt) * 64 + lane) * 8];
        acc = __builtin_amdgcn_mfma_f32_16x16x32_bf16(a[kt], wf, acc, 0, 0, 0);
      }
      float bias = sm.bias1[n * 16 + col];
      #pragma unroll
      for (int j = 0; j < 4; ++j)  // C layout: row=quad*4+j, col
        h1w[(quad * 4 + j) * 72 + n * 16 + col] = f2bf(fmaxf(acc[j] + bias, 0.f));
    }
    bf16x8 a2[2];  // wave-local LDS round-trip (no __syncthreads needed)
    #pragma unroll
    for (int k2 = 0; k2 < 2; ++k2)
      a2[k2] = *(const bf16x8*)&h1w[col * 72 + k2 * 32 + quad * 8];
    float p[4] = {0.f, 0.f, 0.f, 0.f};
    #pragma unroll
    for (int n = 0; n < 4; ++n) {
      bf16x8 w20 = *(const bf16x8*)&sm.flds2[((n * 2 + 0) * 64 + lane) * 8];
      bf16x8 w21 = *(const bf16x8*)&sm.flds2[((n * 2 + 1) * 64 + lane) * 8];
      f32x4 c2 = {0.f, 0.f, 0.f, 0.f};
      c2 = __builtin_amdgcn_mfma_f32_16x16x32_bf16(a2[0], w20, c2, 0, 0, 0);
      c2 = __builtin_amdgcn_mfma_f32_16x16x32_bf16(a2[1], w21, c2, 0, 0, 0);
      float bb = sm.b2s[n * 16 + col];
      float w3 = sm.w3s[n * 16 + col];
      #pragma unroll
      for (int j = 0; j < 4; ++j)
        p[j] = fmaf(fmaxf(c2[j] + bb, 0.f), w3, p[j]);  // layer 3 fused; b3 dropped
    }
    #pragma unroll
    for (int j = 0; j < 4; ++j) {
      #pragma unroll
      for (int off = 1; off < 16; off <<= 1)
        p[j] += __shfl_xor(p[j], off);  // reduce over 16 cols
      if (col == 0) sm.scores[mt * 16 + quad * 4 + j] = p[j];
    }
  };

  load_tile(ka[0], mts[0]);
  load_tile(ka[1], mts[1]);            // prefetch depth 1
  compute_tile(ka[0], mts[0]);
  load_tile(ka[2], mts[2]);
  compute_tile(ka[1], mts[1]);
  if (wv == 0) load_tile(ka[3], 12);
  compute_tile(ka[2], mts[2]);
  if (wv == 0) compute_tile(ka[3], 12);
  __syncthreads();  // scores complete

  // ---- masked softmax over L (fp32; matches ref incl. all-pad handling)
  float sc = (t < LL) ? sm.scores[t] : -3.0e38f;
  float vmax = (my_mask != 0) ? sc : -3.0e38f;
  #pragma unroll
  for (int off = 1; off < 64; off <<= 1) vmax = fmaxf(vmax, __shfl_xor(vmax, off));
  if (lane == 0) sm.red[wv] = vmax;
  __syncthreads();
  float M = fmaxf(fmaxf(sm.red[0], sm.red[1]), fmaxf(sm.red[2], sm.red[3]));
  float ex = (t < LL && my_mask != 0) ? __expf(sc - M) : 0.f;
  float vsum = ex;
  #pragma unroll
  for (int off = 1; off < 64; off <<= 1) vsum += __shfl_xor(vsum, off);
  if (lane == 0) sm.red[4 + wv] = vsum;
  __syncthreads();
  float Z = sm.red[4] + sm.red[5] + sm.red[6] + sm.red[7];
  bool allpad = !(Z > 0.f);
  float rz = allpad ? 0.f : (1.f / Z);
  if (t < 208) sm.scores[t] = (t < LL) ? ex * rz : 0.f;
  __syncthreads();

  // ---- weighted sum from register-resident keys:
  // lane holds keys[mts[i]*16+col][kt*32+quad*8 .. +7]; reduce over col.
  {
    const int nt = (wv == 0) ? 4 : 3;
    float aw[4] = {0.f, 0.f, 0.f, 0.f};
    #pragma unroll
    for (int i = 0; i < 4; ++i)
      if (i < nt) aw[i] = sm.scores[mts[i] * 16 + col];  // rows>=200 -> 0

    float* redf = (float*)&sm.h1[0][0];  // 4 x 128 floats (h1 dead)
    #pragma unroll
    for (int kt = 0; kt < 4; ++kt) {
      float s[8] = {0.f, 0.f, 0.f, 0.f, 0.f, 0.f, 0.f, 0.f};
      #pragma unroll
      for (int i = 0; i < 4; ++i) {
        if (i < nt) {
          const int* kv = (const int*)&ka[i][kt];
          #pragma unroll
          for (int w = 0; w < 4; ++w) {
            unsigned u = (unsigned)kv[w];
            s[2 * w]     = fmaf(aw[i], __uint_as_float(u << 16), s[2 * w]);
            s[2 * w + 1] = fmaf(aw[i], __uint_as_float(u & 0xffff0000u), s[2 * w + 1]);
          }
        }
      }
      #pragma unroll
      for (int j = 0; j < 8; ++j) {
        #pragma unroll
        for (int off = 1; off < 16; off <<= 1)
          s[j] += __shfl_xor(s[j], off);  // reduce over the 16 cols (rows)
      }
      if (col == 0) {
        #pragma unroll
        for (int j = 0; j < 8; ++j)
          redf[wv * 128 + kt * 32 + quad * 8 + j] = s[j];
      }
    }
    __syncthreads();
    if (t < LE) {
      float s = redf[t] + redf[128 + t] + redf[256 + t] + redf[384 + t];
      if (allpad) s = no_hist[t];
      out[b * LE + t] = s;
    }
  }
}

extern "C" void kernel_launch(void* const* d_in, const int* in_sizes, int n_in,
                              void* d_out, int out_size, void* d_ws, size_t ws_size,
                              hipStream_t stream) {
  (void)in_sizes; (void)n_in; (void)ws_size; (void)out_size; (void)d_ws;
  const float* query   = (const float*)d_in[0];
  const float* keysg   = (const float*)d_in[1];
  const int*   mask    = (const int*)d_in[2];
  const float* W1      = (const float*)d_in[3];
  const float* b1      = (const float*)d_in[4];
  const float* W2      = (const float*)d_in[5];
  const float* b2      = (const float*)d_in[6];
  const float* W3      = (const float*)d_in[7];
  // d_in[8] = b3: unused (softmax shift-invariant)
  const float* no_hist = (const float*)d_in[9];

  // d_ws completely unused (weights prepped into __device__ globals each launch)
  k0_prep<<<32, 256, 0, stream>>>(W1, W2);
  din_attn<<<NB, 256, 0, stream>>>(query, keysg, mask, b1, b2, W3, no_hist,
                                   (float*)d_out);
}

// Round 4
// 313.467 us; speedup vs baseline: 1.2235x; 1.0196x over previous
//
#include <hip/hip_runtime.h>

// DIN attention layer: B=2048, L=200, E=128, H=64.  R6: pipe-pressure cut.
// R5 diagnosis: din (~68us) is issue-pipe-bound: memory 34us floor, VALU ~35us
// (f2bf bit-ops), DS ~30us (scalar h1 writes + 600+ shuffle-reduce ops) poorly
// overlapped. This round: (1) v_cvt_pk_bf16_f32 packed converts (keys 96->16
// VALU/tile); (2) layer-1 MFMA operand SWAP: mfma(Wk,keys) -> D[h][l], whose
// C-layout makes h1 writes contiguous 8B (4x ds_write_b64 vs 16x ds_write_b16)
// while layer-2 A-frag reads stay 2x ds_read_b128 (row stride 68); (3) reduce-
// scatter butterflies: score reduce 16->5 shuffles/tile, wsum 128->30 shuffles
// + float2 LDS partials. Same math, RNE conversions -> bit-identical output.

#define NB 2048
#define LE 128   // E
#define LH 64    // H
#define LL 200   // L

typedef short bf16x8 __attribute__((ext_vector_type(8)));
typedef float f32x4 __attribute__((ext_vector_type(4)));

__device__ float g_BD[8192];   // BD[h][e] = W1b - W1d
__device__ float g_Cq[8192];   // Cq[h][e] = W1c
__device__ float g_AD[8192];   // AD[e][h] = W1a + W1d
__device__ short g_W2T[4096];  // W2T[n][k] bf16 (frag-contiguous)

__device__ __forceinline__ short f2bf(float f) {  // RNE float->bf16
  unsigned u = __float_as_uint(f);
  u += 0x7fffu + ((u >> 16) & 1u);
  return (short)(u >> 16);
}

__device__ __forceinline__ unsigned cvtpk(float a, float b) {  // {bf16(a),bf16(b)}
  unsigned d;
  asm("v_cvt_pk_bf16_f32 %0, %1, %2" : "=v"(d) : "v"(a), "v"(b));
  return d;
}

// ---- K0: b-independent weight prep into device globals (no d_ws) ----------
__global__ void k0_prep(const float* __restrict__ W1, const float* __restrict__ W2) {
  int idx = blockIdx.x * 256 + threadIdx.x;  // 32 blocks * 256 = 8192
  if (idx < 8192) {
    int h = idx >> 7, e = idx & 127;
    g_BD[idx] = W1[(128 + e) * LH + h] - W1[(384 + e) * LH + h];
    g_Cq[idx] = W1[(256 + e) * LH + h];
    int e2 = idx >> 6, h2 = idx & 63;
    g_AD[idx] = W1[e2 * LH + h2] + W1[(384 + e2) * LH + h2];
    if (idx < 4096) {
      int c = idx >> 6, k = idx & 63;
      g_W2T[idx] = f2bf(W2[k * LH + c]);
    }
  }
}

struct __align__(16) SM {
  short flds1[16 * 64 * 8];  // 16384 B: W1 frags, frag-major [(n*4+kt)*64+lane]
  short flds2[8 * 64 * 8];   //  8192 B: W2 frags, frag-major [(n*2+k2)*64+lane]
  short h1[4][16 * 68];      //  8704 B: per-wave h1[l][k], row stride 68
  float scores[208];
  float q[128];
  float bias1[64];
  float b2s[64];
  float w3s[64];
  float red[16];
  float redf[512];           //  2048 B: wsum partials [wv][e]
};  // ~37.5 KB -> 4 WG/CU

__global__ void __launch_bounds__(256, 4)
din_attn(const float* __restrict__ query, const float* __restrict__ keysg,
         const int* __restrict__ mask, const float* __restrict__ b1,
         const float* __restrict__ b2, const float* __restrict__ W3,
         const float* __restrict__ no_hist, float* __restrict__ out)
{
  __shared__ SM sm;
  const int b    = blockIdx.x;
  const int t    = threadIdx.x;
  const int lane = t & 63;
  const int wv   = t >> 6;
  const int col  = lane & 15;   // MFMA m/n index
  const int quad = lane >> 4;   // MFMA k-group

  // ---- prologue: tiny loads
  int my_mask = 0;
  if (t < LL) my_mask = mask[b * LL + t];
  if (t < LE) sm.q[t] = query[b * LE + t];
  if (t < LH) { sm.b2s[t] = b2[t]; sm.w3s[t] = W3[t]; }
  __syncthreads();  // q visible

  // Wk[h][e] = BD + q_e*Cq -> bf16, written FRAG-MAJOR into flds1.
  #pragma unroll
  for (int i = 0; i < 4; ++i) {
    int idx = (t + 256 * i) * 8;
    int h = idx >> 7, e0 = idx & 127;
    float4 bd0 = *(const float4*)&g_BD[idx];
    float4 bd1 = *(const float4*)&g_BD[idx + 4];
    float4 c0  = *(const float4*)&g_Cq[idx];
    float4 c1  = *(const float4*)&g_Cq[idx + 4];
    int4 w;
    w.x = (int)cvtpk(bd0.x + sm.q[e0 + 0] * c0.x, bd0.y + sm.q[e0 + 1] * c0.y);
    w.y = (int)cvtpk(bd0.z + sm.q[e0 + 2] * c0.z, bd0.w + sm.q[e0 + 3] * c0.w);
    w.z = (int)cvtpk(bd1.x + sm.q[e0 + 4] * c1.x, bd1.y + sm.q[e0 + 5] * c1.y);
    w.w = (int)cvtpk(bd1.z + sm.q[e0 + 6] * c1.z, bd1.w + sm.q[e0 + 7] * c1.w);
    int n = h >> 4, cc = h & 15, kt = e0 >> 5, qd = (e0 >> 3) & 3;
    *(int4*)&sm.flds1[(((n * 4 + kt) * 64) + qd * 16 + cc) * 8] = w;
  }
  // W2 frags -> flds2 (g_W2T is already frag-contiguous per lane)
  {
    int l = t & 63, f0 = t >> 6;
    #pragma unroll
    for (int ii = 0; ii < 2; ++ii) {
      int f = f0 + ii * 4;  // 0..7
      int n = f >> 1, k2 = f & 1;
      int cc = l & 15, qd = l >> 4;
      *(bf16x8*)&sm.flds2[(f * 64 + l) * 8] =
          *(const bf16x8*)&g_W2T[(n * 16 + cc) * 64 + k2 * 32 + qd * 8];
    }
  }
  // bias1 partials: wave wv sums e-quarter wv (coalesced over h=lane)
  {
    int h = lane;
    float acc = 0.f;
    #pragma unroll 8
    for (int e = wv * 32; e < wv * 32 + 32; ++e)
      acc = fmaf(sm.q[e], g_AD[e * LH + h], acc);
    float* biasp = (float*)&sm.h1[0][0];  // 4 x 64 floats
    biasp[wv * 64 + h] = acc;
  }
  __syncthreads();  // barrier A: flds1/flds2 + partials visible

  if (t < LH) {
    const float* biasp = (const float*)&sm.h1[0][0];
    sm.bias1[t] = b1[t] + biasp[t] + biasp[64 + t] + biasp[128 + t] + biasp[192 + t];
  }
  __syncthreads();  // barrier B: bias1 visible; h1 free for main loop

  // ---- barrier-free main loop: wave wv owns tiles {wv, wv+4, wv+8} (+12 for wv==0)
  const float* kb = keysg + (size_t)b * LL * LE;
  short* h1w = &sm.h1[wv][0];
  const int mts[4] = {wv, wv + 4, wv + 8, 12};
  bf16x8 ka[4][4];  // keys stay resident for the weighted sum

  auto load_tile = [&](bf16x8 (&a)[4], int mt) {
    int row = mt * 16 + col;
    row = row < LL ? row : LL - 1;       // clamp only matters for mt==12
    const float* rp = kb + row * LE;
    #pragma unroll
    for (int kt = 0; kt < 4; ++kt) {
      float4 v0 = *(const float4*)&rp[kt * 32 + quad * 8];
      float4 v1 = *(const float4*)&rp[kt * 32 + quad * 8 + 4];
      int4 w;
      w.x = (int)cvtpk(v0.x, v0.y);
      w.y = (int)cvtpk(v0.z, v0.w);
      w.z = (int)cvtpk(v1.x, v1.y);
      w.w = (int)cvtpk(v1.z, v1.w);
      a[kt] = *(bf16x8*)&w;
    }
  };

  auto compute_tile = [&](const bf16x8 (&a)[4], int mt) {
    // layer 1, operands SWAPPED: D[h][l] = sum_e Wk[h][e]*keys[l][e].
    // Lane (quad,col) holds D rows h=n*16+quad*4+i, col l=col.
    #pragma unroll
    for (int n = 0; n < 4; ++n) {
      f32x4 acc = {0.f, 0.f, 0.f, 0.f};
      #pragma unroll
      for (int kt = 0; kt < 4; ++kt) {
        bf16x8 wf = *(const bf16x8*)&sm.flds1[((n * 4 + kt) * 64 + lane) * 8];
        acc = __builtin_amdgcn_mfma_f32_16x16x32_bf16(wf, a[kt], acc, 0, 0, 0);
      }
      float4 bb = *(const float4*)&sm.bias1[n * 16 + quad * 4];
      // relu + packed convert; h1[l=col][k=n*16+quad*4 + 0..3]: contiguous 8B
      int2 wr;
      wr.x = (int)cvtpk(fmaxf(acc[0] + bb.x, 0.f), fmaxf(acc[1] + bb.y, 0.f));
      wr.y = (int)cvtpk(fmaxf(acc[2] + bb.z, 0.f), fmaxf(acc[3] + bb.w, 0.f));
      *(int2*)&h1w[col * 68 + n * 16 + quad * 4] = wr;
    }
    bf16x8 a2[2];  // wave-local LDS round-trip: A-frag h1[l=col][k-slice]
    #pragma unroll
    for (int k2 = 0; k2 < 2; ++k2)
      a2[k2] = *(const bf16x8*)&h1w[col * 68 + k2 * 32 + quad * 8];
    float p[4] = {0.f, 0.f, 0.f, 0.f};
    #pragma unroll
    for (int n = 0; n < 4; ++n) {
      bf16x8 w20 = *(const bf16x8*)&sm.flds2[((n * 2 + 0) * 64 + lane) * 8];
      bf16x8 w21 = *(const bf16x8*)&sm.flds2[((n * 2 + 1) * 64 + lane) * 8];
      f32x4 c2 = {0.f, 0.f, 0.f, 0.f};
      c2 = __builtin_amdgcn_mfma_f32_16x16x32_bf16(a2[0], w20, c2, 0, 0, 0);
      c2 = __builtin_amdgcn_mfma_f32_16x16x32_bf16(a2[1], w21, c2, 0, 0, 0);
      float bb = sm.b2s[n * 16 + col];
      float w3 = sm.w3s[n * 16 + col];
      #pragma unroll
      for (int j = 0; j < 4; ++j)
        p[j] = fmaf(fmaxf(c2[j] + bb, 0.f), w3, p[j]);  // layer 3 fused; b3 dropped
    }
    // score reduce-scatter over 16 cols: 5 shuffles (was 16)
    {
      bool s8 = (col & 8) != 0;
      float k0 = s8 ? p[2] : p[0], d0 = s8 ? p[0] : p[2];
      float k1 = s8 ? p[3] : p[1], d1 = s8 ? p[1] : p[3];
      k0 += __shfl_xor(d0, 8);
      k1 += __shfl_xor(d1, 8);
      bool s4 = (col & 4) != 0;
      float u = s4 ? k1 : k0, du = s4 ? k0 : k1;
      u += __shfl_xor(du, 4);
      u += __shfl_xor(u, 2);
      u += __shfl_xor(u, 1);
      if ((col & 3) == 0) sm.scores[mt * 16 + quad * 4 + (col >> 2)] = u;
    }
  };

  load_tile(ka[0], mts[0]);
  load_tile(ka[1], mts[1]);            // prefetch depth 1
  compute_tile(ka[0], mts[0]);
  load_tile(ka[2], mts[2]);
  compute_tile(ka[1], mts[1]);
  if (wv == 0) load_tile(ka[3], 12);
  compute_tile(ka[2], mts[2]);
  if (wv == 0) compute_tile(ka[3], 12);
  __syncthreads();  // scores complete

  // ---- masked softmax over L (fp32; matches ref incl. all-pad handling)
  float sc = (t < LL) ? sm.scores[t] : -3.0e38f;
  float vmax = (my_mask != 0) ? sc : -3.0e38f;
  #pragma unroll
  for (int off = 1; off < 64; off <<= 1) vmax = fmaxf(vmax, __shfl_xor(vmax, off));
  if (lane == 0) sm.red[wv] = vmax;
  __syncthreads();
  float M = fmaxf(fmaxf(sm.red[0], sm.red[1]), fmaxf(sm.red[2], sm.red[3]));
  float ex = (t < LL && my_mask != 0) ? __expf(sc - M) : 0.f;
  float vsum = ex;
  #pragma unroll
  for (int off = 1; off < 64; off <<= 1) vsum += __shfl_xor(vsum, off);
  if (lane == 0) sm.red[4 + wv] = vsum;
  __syncthreads();
  float Z = sm.red[4] + sm.red[5] + sm.red[6] + sm.red[7];
  bool allpad = !(Z > 0.f);
  float rz = allpad ? 0.f : (1.f / Z);
  if (t < 208) sm.scores[t] = (t < LL) ? ex * rz : 0.f;
  __syncthreads();

  // ---- weighted sum from register-resident keys (reduce-scatter butterfly)
  {
    const int nt = (wv == 0) ? 4 : 3;
    float v[32];
    #pragma unroll
    for (int k = 0; k < 32; ++k) v[k] = 0.f;
    #pragma unroll
    for (int i = 0; i < 4; ++i) {
      if (i < nt) {
        float aw = sm.scores[mts[i] * 16 + col];  // rows>=200 -> 0
        #pragma unroll
        for (int kt = 0; kt < 4; ++kt) {
          const int* kv = (const int*)&ka[i][kt];
          #pragma unroll
          for (int w = 0; w < 4; ++w) {
            unsigned u = (unsigned)kv[w];
            v[kt * 8 + 2 * w]     = fmaf(aw, __uint_as_float(u << 16), v[kt * 8 + 2 * w]);
            v[kt * 8 + 2 * w + 1] = fmaf(aw, __uint_as_float(u & 0xffff0000u), v[kt * 8 + 2 * w + 1]);
          }
        }
      }
    }
    // value-splitting butterfly over the 16 cols: 30 shuffles (was 128)
    #pragma unroll
    for (int step = 0; step < 4; ++step) {
      const int off  = 8 >> step;
      const int half = 16 >> step;
      bool sel = (col & off) != 0;
      #pragma unroll
      for (int k = 0; k < 16; ++k) {
        if (k < half) {
          float keep = sel ? v[k + half] : v[k];
          float send = sel ? v[k] : v[k + half];
          v[k] = keep + __shfl_xor(send, off);
        }
      }
    }
    // lane holds e0=(col>>2)*32+quad*8+2*(col&3) and e0+1, summed over 16 rows
    int e0 = (col >> 2) * 32 + quad * 8 + ((col & 3) * 2);
    *(float2*)&sm.redf[wv * 128 + e0] = make_float2(v[0], v[1]);
    __syncthreads();
    if (t < LE) {
      float s = sm.redf[t] + sm.redf[128 + t] + sm.redf[256 + t] + sm.redf[384 + t];
      if (allpad) s = no_hist[t];
      out[b * LE + t] = s;
    }
  }
}

extern "C" void kernel_launch(void* const* d_in, const int* in_sizes, int n_in,
                              void* d_out, int out_size, void* d_ws, size_t ws_size,
                              hipStream_t stream) {
  (void)in_sizes; (void)n_in; (void)ws_size; (void)out_size; (void)d_ws;
  const float* query   = (const float*)d_in[0];
  const float* keysg   = (const float*)d_in[1];
  const int*   mask    = (const int*)d_in[2];
  const float* W1      = (const float*)d_in[3];
  const float* b1      = (const float*)d_in[4];
  const float* W2      = (const float*)d_in[5];
  const float* b2      = (const float*)d_in[6];
  const float* W3      = (const float*)d_in[7];
  // d_in[8] = b3: unused (softmax shift-invariant)
  const float* no_hist = (const float*)d_in[9];

  k0_prep<<<32, 256, 0, stream>>>(W1, W2);
  din_attn<<<NB, 256, 0, stream>>>(query, keysg, mask, b1, b2, W3, no_hist,
                                   (float*)d_out);
}